// Round 10
// baseline (300.047 us; speedup 1.0000x reference)
//
#include <hip/hip_runtime.h>
#include <hip/hip_bf16.h>
#include <math.h>

// Problem constants (CPUEfficientCausalAttention): B=2, S=2048, HIDDEN=1024, H=16, hd=64
#define HIDDEN 1024
#define HEADS 16
#define HDIM 64
#define BATCH 2
#define SEQ 2048
#define BHN (BATCH*HEADS)   // 32
#define MTOT (BATCH*SEQ)    // 4096

typedef __attribute__((ext_vector_type(8))) short short8;   // 8 bf16 (16x16x32 A/B frag)
typedef __attribute__((ext_vector_type(4))) short short4v;  // 4 bf16 (16x16x16 A/B frag)
typedef __attribute__((ext_vector_type(4))) float floatx4;  // MFMA C/D frag

// global -> LDS direct (16B per lane; LDS dst is wave-uniform base, +lane*16 implicit)
#define GL2LDS(gsrc, ldst) __builtin_amdgcn_global_load_lds( \
    (const __attribute__((address_space(1))) void*)(gsrc), \
    (__attribute__((address_space(3))) void*)(ldst), 16, 0, 0)

__device__ __forceinline__ short f2bf(float f) {
  union { float f; unsigned u; } v; v.f = f;
  unsigned u = v.u;
  unsigned r = (u + 0x7fffu + ((u >> 16) & 1u)) >> 16;  // RNE
  return (short)r;
}
__device__ __forceinline__ short8 cat4(short4v a, short4v b) {
  return __builtin_shufflevector(a, b, 0, 1, 2, 3, 4, 5, 6, 7);
}

// One fused fp32->bf16 cast for x (1048576 vec4), qkv_w (786432), out_w (262144)
__global__ __launch_bounds__(256) void cvt3_f32_bf16(
    const float* __restrict__ a, const float* __restrict__ b, const float* __restrict__ c,
    short* __restrict__ oa, short* __restrict__ ob, short* __restrict__ oc) {
  int i = blockIdx.x * 256 + threadIdx.x;
  const float* src; short* dst; int j;
  if (i < 1048576)      { src = a; dst = oa; j = i; }
  else if (i < 1835008) { src = b; dst = ob; j = i - 1048576; }
  else                  { src = c; dst = oc; j = i - 1835008; }
  float4 f = reinterpret_cast<const float4*>(src)[j];
  short4 o;
  o.x = f2bf(f.x); o.y = f2bf(f.y); o.z = f2bf(f.z); o.w = f2bf(f.w);
  reinterpret_cast<short4*>(dst)[j] = o;
}

// C[M,N] = A[M,K] @ B[N,K]^T, bf16 in, fp32 accum.
// 128xBN tile, BK=64 (XOR-swizzled LDS rows of 128B keep b128 reads bank-minimal),
// 4 waves in 2x2, each wave 64x(BN/2).
// EPI==1 (BN=128): scatter qkv epilogue (q scaled by hd^-0.5*log2e, k row-major,
//   v transposed with PACKED 8B stores: acc r=0..3 are s-consecutive = contiguous in V^T)
// EPI==2: plain fp32 C row-major
template<int EPI, int BN>
__global__ __launch_bounds__(256) void gemm_bt(
    const short* __restrict__ A, const short* __restrict__ B,
    int M, int N, int K,
    float* __restrict__ outF,
    short* __restrict__ outQ, short* __restrict__ outK, short* __restrict__ outV)
{
  constexpr int WN = BN / 2;   // wave col extent
  constexpr int NI = BN / 32;  // 16-col tiles per wave
  __shared__ __align__(16) short As[128*64];
  __shared__ __align__(16) short Bs[BN*64];
  const int tid = threadIdx.x;
  const int wv = tid >> 6;
  const int lane = tid & 63;
  const int l15 = lane & 15;
  const int quad = lane >> 4;
  const int swl = l15 & 7;
  const int wm = wv >> 1, wn = wv & 1;
  const int row0 = blockIdx.y * 128, col0 = blockIdx.x * BN;

  floatx4 acc[4][NI];
#pragma unroll
  for (int i = 0; i < 4; i++)
#pragma unroll
    for (int j = 0; j < NI; j++) acc[i][j] = (floatx4){0.f, 0.f, 0.f, 0.f};

  for (int k0 = 0; k0 < K; k0 += 64) {
    // stage A [128][64] (1024 16B-chunks) and B [BN][64], XOR-swizzled on source col
#pragma unroll
    for (int rd = 0; rd < 4; ++rd) {
      int chunk = rd * 256 + tid;
      int r = chunk >> 3, c = ((chunk & 7) ^ (r & 7)) << 3;
      GL2LDS(A + (long)(row0 + r) * K + k0 + c, As + (rd * 256 + wv * 64) * 8);
    }
#pragma unroll
    for (int rd = 0; rd < BN / 32; ++rd) {
      int chunk = rd * 256 + tid;
      int r = chunk >> 3, c = ((chunk & 7) ^ (r & 7)) << 3;
      GL2LDS(B + (long)(col0 + r) * K + k0 + c, Bs + (rd * 256 + wv * 64) * 8);
    }
    __syncthreads();

    short8 af[4][2], bfr[NI][2];
#pragma unroll
    for (int mi = 0; mi < 4; mi++) {
      const short* ap = As + (wm * 64 + mi * 16 + l15) * 64;
#pragma unroll
      for (int kk = 0; kk < 2; kk++)
        af[mi][kk] = *(const short8*)(ap + (((kk * 4 + quad) ^ swl) << 3));
    }
#pragma unroll
    for (int ni = 0; ni < NI; ni++) {
      const short* bp = Bs + (wn * WN + ni * 16 + l15) * 64;
#pragma unroll
      for (int kk = 0; kk < 2; kk++)
        bfr[ni][kk] = *(const short8*)(bp + (((kk * 4 + quad) ^ swl) << 3));
    }
#pragma unroll
    for (int mi = 0; mi < 4; mi++)
#pragma unroll
      for (int ni = 0; ni < NI; ni++)
#pragma unroll
        for (int kk = 0; kk < 2; kk++)
          acc[mi][ni] = __builtin_amdgcn_mfma_f32_16x16x32_bf16(af[mi][kk], bfr[ni][kk], acc[mi][ni], 0, 0, 0);
    __syncthreads();
  }

  if (EPI == 2) {
#pragma unroll
    for (int mi = 0; mi < 4; mi++) {
      int rr = row0 + wm * 64 + mi * 16 + quad * 4;
#pragma unroll
      for (int ni = 0; ni < NI; ni++) {
        int cc = col0 + wn * WN + ni * 16 + l15;
#pragma unroll
        for (int r = 0; r < 4; r++)
          outF[(long)(rr + r) * N + cc] = acc[mi][ni][r];
      }
    }
  } else {
    // qkv scatter: j = t*1024 + h*64 + d ; i = b*2048 + s
#pragma unroll
    for (int mi = 0; mi < 4; mi++) {
      int rowg = row0 + wm * 64 + mi * 16 + quad * 4;
      int b = rowg >> 11, s0 = rowg & 2047;    // constant across r (rowg % 4 == 0)
#pragma unroll
      for (int ni = 0; ni < NI; ni++) {
        int j = col0 + wn * WN + ni * 16 + l15;
        int t = j >> 10;
        int rem = j & 1023;
        int h = rem >> 6, d = rem & 63;
        int bh = b * HEADS + h;
        if (t == 2) {
          // v transposed: 4 s-consecutive values -> one 8B store
          short4 pk;
          pk.x = f2bf(acc[mi][ni][0]); pk.y = f2bf(acc[mi][ni][1]);
          pk.z = f2bf(acc[mi][ni][2]); pk.w = f2bf(acc[mi][ni][3]);
          *(short4*)(outV + (long)(bh * HDIM + d) * SEQ + s0) = pk;
        } else {
#pragma unroll
          for (int r = 0; r < 4; r++) {
            float v = acc[mi][ni][r];
            // q scale = hd^-0.5 * log2(e) so flash can use raw v_exp_f32 (2^x)
            if (t == 0) outQ[(bh * SEQ + s0 + r) * HDIM + d] = f2bf(v * 0.18033688011112042f);
            else        outK[(bh * SEQ + s0 + r) * HDIM + d] = f2bf(v);
          }
        }
      }
    }
  }
}

// K tile staging (K only; 64x64 bf16 = 8KB = 512 16B-chunks / 128 threads), XOR-swizzled.
__device__ __forceinline__ void stage_k(const short* __restrict__ kg,
                                        int bh, int kt, short* KsB,
                                        int tid, int wv) {
#pragma unroll
  for (int i = 0; i < 4; ++i) {
    int slot = i * 128 + tid;                 // 0..511
    int r = slot >> 3;
    int sc = ((slot & 7) ^ (r & 7)) << 3;
    GL2LDS(kg + (bh * SEQ + kt * 64 + r) * HDIM + sc, KsB + (i * 128 + wv * 64) * 8);
  }
}

// Flash attention v10: K staged (GL2LDS double-buffer, latency-decoupled), V DIRECT
// from global (issued before S-MFMA: ~500cyc slack; PV waits vmcnt(4), never a drain).
// LDS 16KB -> high blocks/CU. v_perm bf16 packing (1 instr per pair vs 3).
//  - S^T = K.Q^T (16x16x32); S^T C-layout == K=16 A-layout -> P in registers;
//    PV at K=32 via permuted-k concat; lsum via P @ ones. Static-max exp2 softmax.
//  - grid (bh, 32), rt = 31-y (LPT); bh ≡ linear-id (mod 8) -> per-XCD K/V L2 affinity.
__global__ __launch_bounds__(128, 4) void flash_attn(
    const short* __restrict__ qg, const short* __restrict__ kg,
    const short* __restrict__ vT, short* __restrict__ attn)
{
  __shared__ __align__(16) short Ks[2][64 * 64];

  const int tid = threadIdx.x;
  const int wv = tid >> 6, lane = tid & 63;
  const int l15 = lane & 15, quad = lane >> 4;
  const int swl = l15 & 7;
  const int bh = blockIdx.x;
  const int rt = 31 - (int)blockIdx.y;      // longest blocks dispatch first (global LPT)
  const int m0 = rt * 64 + wv * 32;         // wave's first q row

  const short* vbase = vT + (long)bh * HDIM * SEQ;

  // Q frags (persistent): B-operand for S^T: n=q=m0+mi*16+l15, k=d=kk*32+quad*8+j
  short8 aq[2][2];
#pragma unroll
  for (int mi = 0; mi < 2; mi++) {
    const short* qp = qg + (long)(bh * SEQ + m0 + mi * 16 + l15) * HDIM + quad * 8;
    aq[mi][0] = *(const short8*)qp;
    aq[mi][1] = *(const short8*)(qp + 32);
  }

  const short ONE = (short)0x3F80;  // bf16 1.0
  const short8 ones8 = {ONE, ONE, ONE, ONE, ONE, ONE, ONE, ONE};

  floatx4 o[2][4], lsum[2];
#pragma unroll
  for (int mi = 0; mi < 2; mi++) {
    lsum[mi] = (floatx4){0.f, 0.f, 0.f, 0.f};
#pragma unroll
    for (int nt = 0; nt < 4; nt++) o[mi][nt] = (floatx4){0.f, 0.f, 0.f, 0.f};
  }

  const int ntiles = rt + 1;
  stage_k(kg, bh, 0, Ks[0], tid, wv);

  for (int kt = 0; kt < ntiles; ++kt) {
    __syncthreads();                         // drains GL2LDS (vmcnt 0): Ks[kt&1] ready
    const int buf = kt & 1;

    // ---- V loads FIRST (direct global; consumed at PV -> waits vmcnt(4) only) ----
    short4v vlo[4][2], vhi[4][2];
#pragma unroll
    for (int nt = 0; nt < 4; nt++) {
      const short* vp = vbase + (nt * 16 + l15) * SEQ + kt * 64 + quad * 4;
#pragma unroll
      for (int g32 = 0; g32 < 2; g32++) {
        vlo[nt][g32] = *(const short4v*)(vp + g32 * 32);
        vhi[nt][g32] = *(const short4v*)(vp + g32 * 32 + 16);
      }
    }

    // ---- prefetch next K tile (in flight until next barrier) ----
    if (kt + 1 < ntiles)
      stage_k(kg, bh, kt + 1, Ks[buf ^ 1], tid, wv);

    const short* KsB = Ks[buf];

#pragma unroll
    for (int mi = 0; mi < 2; mi++) {
      // ---- S^T = K . Q^T (16x16x32): D[row=kpos(quad*4+r)][col=q(l15)] ----
      floatx4 sc[4];
#pragma unroll
      for (int nh = 0; nh < 4; nh++) sc[nh] = (floatx4){0.f, 0.f, 0.f, 0.f};
#pragma unroll
      for (int nh = 0; nh < 4; nh++) {
        const short* kp = KsB + (nh * 16 + l15) * 64;
        short8 kf0 = *(const short8*)(kp + ((quad ^ swl) << 3));         // k=d 0..31
        short8 kf1 = *(const short8*)(kp + (((4 + quad) ^ swl) << 3));   // k=d 32..63
        sc[nh] = __builtin_amdgcn_mfma_f32_16x16x32_bf16(kf0, aq[mi][0], sc[nh], 0, 0, 0);
        sc[nh] = __builtin_amdgcn_mfma_f32_16x16x32_bf16(kf1, aq[mi][1], sc[nh], 0, 0, 0);
      }

      // ---- softmax (static max, exp2 domain) + v_perm bf16 pack (registers) ----
      short4v pa[4];
      const int qrow = m0 + mi * 16 + l15;
      const bool full = (kt * 64 + 63) <= (m0 + mi * 16);   // wave-uniform per mi
#pragma unroll
      for (int nh = 0; nh < 4; nh++) {
        unsigned u[4];
#pragma unroll
        for (int r2 = 0; r2 < 4; r2++) {
          float pe = __builtin_amdgcn_exp2f(sc[nh][r2]);
          if (!full) {
            const int kpos = kt * 64 + nh * 16 + quad * 4 + r2;
            pe = (kpos <= qrow) ? pe : 0.f;
          }
          u[r2] = __builtin_bit_cast(unsigned, pe);
        }
        uint2 w;   // truncate-to-bf16 pack: one v_perm per pair
        w.x = __builtin_amdgcn_perm(u[1], u[0], 0x07060302u);  // kpos quad*4+{0,1}
        w.y = __builtin_amdgcn_perm(u[3], u[2], 0x07060302u);  // kpos quad*4+{2,3}
        pa[nh] = __builtin_bit_cast(short4v, w);
      }

      // ---- P @ V and P @ ones at K=32 (permuted-k concat) ----
#pragma unroll
      for (int g32 = 0; g32 < 2; g32++) {
        const short8 a32 = cat4(pa[2 * g32], pa[2 * g32 + 1]);
        lsum[mi] = __builtin_amdgcn_mfma_f32_16x16x32_bf16(a32, ones8, lsum[mi], 0, 0, 0);
#pragma unroll
        for (int nt = 0; nt < 4; nt++)
          o[mi][nt] = __builtin_amdgcn_mfma_f32_16x16x32_bf16(
              a32, cat4(vlo[nt][g32], vhi[nt][g32]), o[mi][nt], 0, 0, 0);
      }
    }
  }

  const int b = bh >> 4, h = bh & 15;
#pragma unroll
  for (int mi = 0; mi < 2; mi++)
#pragma unroll
    for (int r2 = 0; r2 < 4; r2++) {
      const float inv = 1.0f / lsum[mi][r2];
      const int s = m0 + mi * 16 + quad * 4 + r2;
#pragma unroll
      for (int nt = 0; nt < 4; nt++)
        attn[(long)(b * SEQ + s) * HIDDEN + h * HDIM + nt * 16 + l15] = f2bf(o[mi][nt][r2] * inv);
    }
}

extern "C" void kernel_launch(void* const* d_in, const int* in_sizes, int n_in,
                              void* d_out, int out_size, void* d_ws, size_t ws_size,
                              hipStream_t stream) {
  const float* x     = (const float*)d_in[0];  // [2,2048,1024]
  const float* qkv_w = (const float*)d_in[1];  // [3072,1024]
  const float* out_w = (const float*)d_in[2];  // [1024,1024]
  float* out = (float*)d_out;                  // [2,2048,1024] fp32

  short* xb   = (short*)d_ws;                       // 4096*1024
  short* wqb  = xb  + MTOT * HIDDEN;                // 3072*1024
  short* wob  = wqb + 3 * HIDDEN * HIDDEN;          // 1024*1024
  short* qB   = wob + HIDDEN * HIDDEN;              // 32*2048*64
  short* kB   = qB  + BHN * SEQ * HDIM;
  short* vTB  = kB  + BHN * SEQ * HDIM;
  short* attn = vTB + BHN * SEQ * HDIM;             // 4096*1024

  // fused bf16 casts: (4096+3072+1024)*1024/4 = 2097152 vec4 -> 8192 blocks
  cvt3_f32_bf16<<<dim3(8192), dim3(256), 0, stream>>>(x, qkv_w, out_w, xb, wqb, wob);

  // QKV projection: M=4096, N=3072, K=1024, BK=64
  gemm_bt<1, 128><<<dim3(3 * HIDDEN / 128, MTOT / 128), dim3(256), 0, stream>>>(
      xb, wqb, MTOT, 3 * HIDDEN, HIDDEN, nullptr, qB, kB, vTB);

  // causal attention: 64-row 2-wave blocks, K staged / V direct, LPT order
  flash_attn<<<dim3(BHN, SEQ / 64), dim3(128), 0, stream>>>(qB, kB, vTB, attn);

  // output projection: M=4096, N=1024, K=1024 (128x64 tiles -> 512 blocks), BK=64
  gemm_bt<2, 64><<<dim3(HIDDEN / 64, MTOT / 128), dim3(256), 0, stream>>>(
      attn, wob, MTOT, HIDDEN, HIDDEN, out, nullptr, nullptr, nullptr);
}